// Round 1
// baseline (165.840 us; speedup 1.0000x reference)
//
#include <hip/hip_runtime.h>
#include <cstdint>

// =====================================================================
// MultiHeadAttention_84576495993495
//
// Algebraic collapse: einsum('bhqk,bhvo->bhvo', attn, v) sums attn over
// BOTH q and k; softmax rows sum to 1, so the factor is exactly S=2048.
//   final = 2048 * x @ (Wp@Wv)^T + (2048*Wp@bv + bp)
// Wq/bq/Wk/bk are unused.
//
// Pipeline:
//   1. convert x  (f32 -> bf16)                 [8192,1024]
//   2. convert Wp (f32 -> bf16)                 [1024,1024]
//   3. transpose+convert Wv -> Wv^T bf16        [1024,1024] (so GEMM is NT)
//   4. c[n] = 2048*dot(Wp[n,:], bv) + bp[n]     (fp32, exact-ish)
//   5. M2 = bf16( 2048 * Wp @ Wv )   via NT MFMA GEMM (A=Wp, B=Wv^T)
//   6. out = x @ M2^T + c            via NT MFMA GEMM (A=x,  B=M2), fp32 out
// =====================================================================

typedef unsigned short u16;
typedef __bf16 bf16x8 __attribute__((ext_vector_type(8)));
typedef float f32x4 __attribute__((ext_vector_type(4)));

__device__ __forceinline__ u16 f2bf(float f) {
  // round-to-nearest-even f32 -> bf16 bits (inputs are finite/normal)
  unsigned int u = __float_as_uint(f);
  u += 0x7fffu + ((u >> 16) & 1u);
  return (u16)(u >> 16);
}

// async global->LDS 16B copy; LDS dest = wave-uniform base + lane*16
__device__ __forceinline__ void load16(const void* g, void* l) {
  auto gp = (const __attribute__((address_space(1))) unsigned int*)(uintptr_t)g;
  // generic LDS ptr: low 32 bits are the LDS offset (aperture is 2^32-aligned)
  auto lp = (__attribute__((address_space(3))) unsigned int*)(unsigned int)(uintptr_t)l;
  __builtin_amdgcn_global_load_lds(gp, lp, 16, 0, 0);
}

// ---------------------------------------------------------------------
// f32 -> bf16 conversion, 4 elements/thread
__global__ void k_conv(const float* __restrict__ src, u16* __restrict__ dst) {
  const long i = (long)(blockIdx.x * blockDim.x + threadIdx.x) * 4;
  const float4 v = *(const float4*)(src + i);
  ushort4 o;
  o.x = f2bf(v.x); o.y = f2bf(v.y); o.z = f2bf(v.z); o.w = f2bf(v.w);
  *(ushort4*)(dst + i) = o;
}

// ---------------------------------------------------------------------
// Wv [j][i] f32  ->  dst [i][j] bf16   (1024x1024, 32x32 LDS tiles)
__global__ void k_transpose_conv(const float* __restrict__ src, u16* __restrict__ dst) {
  __shared__ float tile[32][33];
  const int bi = blockIdx.x * 32;  // output row block (i)
  const int bj = blockIdx.y * 32;  // output col block (j) = src row block
  const int tx = threadIdx.x & 31;
  const int ty = threadIdx.x >> 5;  // 0..7
  for (int r = ty; r < 32; r += 8)
    tile[r][tx] = src[(long)(bj + r) * 1024 + bi + tx];
  __syncthreads();
  for (int r = ty; r < 32; r += 8)
    dst[(long)(bi + r) * 1024 + bj + tx] = f2bf(tile[tx][r]);
}

// ---------------------------------------------------------------------
// c[n] = 2048*dot(Wp[n,:], bv) + bp[n]    (one wave per row, fp32)
__global__ void k_bias(const float* __restrict__ Wp, const float* __restrict__ bv,
                       const float* __restrict__ bp, float* __restrict__ c) {
  const int row = blockIdx.x * 4 + (threadIdx.x >> 6);
  const int lane = threadIdx.x & 63;
  const float* w = Wp + (long)row * 1024;
  float s = 0.f;
  for (int j = lane; j < 1024; j += 64) s += w[j] * bv[j];
  for (int off = 32; off; off >>= 1) s += __shfl_down(s, off, 64);
  if (lane == 0) c[row] = 2048.f * s + bp[row];
}

// ---------------------------------------------------------------------
// NT bf16 GEMM: Out[M,N] = scale * A[M,K] @ B[N,K]^T (+ bias[n])
// 128x128 tile, BK=32, 256 threads = 4 waves (2x2), each wave 64x64.
// m97 structure: global_load_lds width=16 staging, 16x16x32 MFMA.
template <bool OUT_BF16>
__global__ __launch_bounds__(256, 3) void k_gemm_nt(
    const u16* __restrict__ A, const u16* __restrict__ B, void* __restrict__ Out,
    const float* __restrict__ bias, int M, int N, int K, float scale) {
  __shared__ u16 As[128 * 32];  // [row m][k 0..31], flat (no pad: global_load_lds)
  __shared__ u16 Bs[128 * 32];  // [row n][k 0..31]

  const int tid = threadIdx.x;
  const int lane = tid & 63;
  const int wv = tid >> 6;
  const int waveM = (wv & 1) << 6;   // 0 / 64
  const int waveN = (wv >> 1) << 6;  // 0 / 64
  const int l15 = lane & 15;
  const int quad = lane >> 4;

  const long bm = (long)blockIdx.x * 128;
  const long bn = (long)blockIdx.y * 128;

  // staging: thread tid loads 8 bf16 at (row = tid/4 [+64], col = (tid%4)*8)
  const int srow = tid >> 2;
  const int scol = (tid & 3) << 3;
  const u16* Ag = A + (bm + srow) * K + scol;
  const u16* Bg = B + (bn + srow) * K + scol;
  u16* As0 = As + wv * 512;         // wave-uniform LDS bases
  u16* As1 = As + 2048 + wv * 512;
  u16* Bs0 = Bs + wv * 512;
  u16* Bs1 = Bs + 2048 + wv * 512;

  const f32x4 zero = {0.f, 0.f, 0.f, 0.f};
  f32x4 acc[4][4];
#pragma unroll
  for (int i = 0; i < 4; ++i)
#pragma unroll
    for (int j = 0; j < 4; ++j) acc[i][j] = zero;

  for (int k0 = 0; k0 < K; k0 += 32) {
    __syncthreads();  // previous tile fully consumed
    load16(Ag + k0, As0);
    load16(Ag + (long)64 * K + k0, As1);
    load16(Bg + k0, Bs0);
    load16(Bg + (long)64 * K + k0, Bs1);
    __syncthreads();  // emits s_waitcnt vmcnt(0) before s_barrier: staging done

    bf16x8 af[4], bg[4];
#pragma unroll
    for (int t = 0; t < 4; ++t) {
      // A-frag: A[m = l15][k = quad*8 + j]; B-frag: B[n = l15][k = quad*8 + j]
      af[t] = *(const bf16x8*)(As + (waveM + t * 16 + l15) * 32 + quad * 8);
      bg[t] = *(const bf16x8*)(Bs + (waveN + t * 16 + l15) * 32 + quad * 8);
    }
#pragma unroll
    for (int i = 0; i < 4; ++i)
#pragma unroll
      for (int j = 0; j < 4; ++j)
        acc[i][j] = __builtin_amdgcn_mfma_f32_16x16x32_bf16(af[i], bg[j], acc[i][j], 0, 0, 0);
  }

  // epilogue: C/D layout col = lane&15, row = (lane>>4)*4 + reg  [m89/m91]
#pragma unroll
  for (int i = 0; i < 4; ++i) {
    const long gm = bm + waveM + i * 16 + quad * 4;
#pragma unroll
    for (int j = 0; j < 4; ++j) {
      const long gn = bn + waveN + j * 16 + l15;
      const float bb = (bias != nullptr) ? bias[gn] : 0.f;
#pragma unroll
      for (int r = 0; r < 4; ++r) {
        const float val = acc[i][j][r] * scale + bb;
        if constexpr (OUT_BF16)
          ((u16*)Out)[(gm + r) * N + gn] = f2bf(val);
        else
          ((float*)Out)[(gm + r) * N + gn] = val;
      }
    }
  }
}

// =====================================================================
extern "C" void kernel_launch(void* const* d_in, const int* in_sizes, int n_in,
                              void* d_out, int out_size, void* d_ws, size_t ws_size,
                              hipStream_t stream) {
  // setup_inputs order: x, Wq, bq, Wk, bk, Wv, bv, Wp, bp
  const float* x  = (const float*)d_in[0];
  const float* Wv = (const float*)d_in[5];
  const float* bv = (const float*)d_in[6];
  const float* Wp = (const float*)d_in[7];
  const float* bp = (const float*)d_in[8];

  char* ws = (char*)d_ws;
  u16* xb   = (u16*)(ws);                              // 16,777,216 B
  u16* wpb  = (u16*)(ws + 16777216);                   //  2,097,152 B
  u16* wvtb = (u16*)(ws + 16777216 + 2097152);         //  2,097,152 B
  u16* m2b  = (u16*)(ws + 16777216 + 2 * 2097152);     //  2,097,152 B
  float* cv = (float*)(ws + 16777216 + 3 * 2097152);   //      4,096 B

  // conversions / transpose / bias (independent, ~12 us total)
  k_conv<<<8192, 256, 0, stream>>>(x, xb);                      // 8.4M elems
  k_conv<<<1024, 256, 0, stream>>>(Wp, wpb);                    // 1M elems
  k_transpose_conv<<<dim3(32, 32), 256, 0, stream>>>(Wv, wvtb);
  k_bias<<<256, 256, 0, stream>>>(Wp, bv, bp, cv);

  // M2 = bf16(2048 * Wp @ Wv)   [1024,1024] = A(Wp) @ B(Wv^T)^T
  k_gemm_nt<true><<<dim3(8, 8), 256, 0, stream>>>(wpb, wvtb, m2b, nullptr,
                                                  1024, 1024, 1024, 2048.f);
  // out = x @ M2^T + c          [8192,1024] fp32
  k_gemm_nt<false><<<dim3(64, 8), 256, 0, stream>>>(xb, m2b, d_out, cv,
                                                    8192, 1024, 1024, 1.f);
}

// Round 2
// 149.017 us; speedup vs baseline: 1.1129x; 1.1129x over previous
//
#include <hip/hip_runtime.h>
#include <cstdint>

// =====================================================================
// MultiHeadAttention_84576495993495  (round 2)
//
// Algebraic collapse: einsum('bhqk,bhvo->bhvo', attn, v) sums attn over
// BOTH q and k; softmax rows sum to 1 -> factor is exactly S=2048.
//   final = x @ (2048*Wp@Wv)^T + (2048*Wp@bv + bp)
// Wq/bq/Wk/bk unused.
//
// R2 changes (block-count starvation was the R1 bottleneck):
//   - prep fused into ONE kernel (conv x, conv Wp, transpose Wv, bias)
//   - GEMM1 (1024^3) split-K=4 -> 256 blocks (was 64), fp32 partials +
//     reduce kernel that applies *2048 and converts to bf16
//   - GEMM2 (8192x1024x1024) tile 128x64 -> 1024 blocks = 4/CU (was 2/CU)
// =====================================================================

typedef unsigned short u16;
typedef __bf16 bf16x8 __attribute__((ext_vector_type(8)));
typedef float f32x4 __attribute__((ext_vector_type(4)));

__device__ __forceinline__ u16 f2bf(float f) {
  // round-to-nearest-even f32 -> bf16 bits (finite inputs)
  unsigned int u = __float_as_uint(f);
  u += 0x7fffu + ((u >> 16) & 1u);
  return (u16)(u >> 16);
}

// async global->LDS 16B copy; LDS dest = wave-uniform base + lane*16
__device__ __forceinline__ void load16(const void* g, void* l) {
  auto gp = (const __attribute__((address_space(1))) unsigned int*)(uintptr_t)g;
  auto lp = (__attribute__((address_space(3))) unsigned int*)(unsigned int)(uintptr_t)l;
  __builtin_amdgcn_global_load_lds(gp, lp, 16, 0, 0);
}

// ---------------------------------------------------------------------
// Fused prep. Block ranges:
//   [0,8192)      conv x   f32->bf16 (4 elem/thread)
//   [8192,9216)   conv Wp  f32->bf16
//   [9216,10240)  transpose+conv Wv -> Wv^T bf16 (32x32 tiles)
//   [10240,10496) cv[n] = 2048*dot(Wp[n,:],bv) + bp[n]
__global__ void k_prep(const float* __restrict__ x, const float* __restrict__ Wv,
                       const float* __restrict__ bv, const float* __restrict__ Wp,
                       const float* __restrict__ bp, u16* __restrict__ xb,
                       u16* __restrict__ wpb, u16* __restrict__ wvtb,
                       float* __restrict__ cv) {
  __shared__ float tile[32][33];
  const int b = blockIdx.x;
  const int tid = threadIdx.x;
  if (b < 9216) {  // conversions
    const float* src = (b < 8192) ? x : Wp;
    u16* dst = (b < 8192) ? xb : wpb;
    const long base = (long)((b < 8192) ? b : (b - 8192)) * 1024 + tid * 4;
    const float4 v = *(const float4*)(src + base);
    ushort4 o;
    o.x = f2bf(v.x); o.y = f2bf(v.y); o.z = f2bf(v.z); o.w = f2bf(v.w);
    *(ushort4*)(dst + base) = o;
  } else if (b < 10240) {  // transpose Wv
    const int tb = b - 9216;
    const int bi = (tb & 31) * 32;   // output row block (i)
    const int bj = (tb >> 5) * 32;   // output col block (j) = src row block
    const int tx = tid & 31;
    const int ty = tid >> 5;  // 0..7
    for (int r = ty; r < 32; r += 8)
      tile[r][tx] = Wv[(long)(bj + r) * 1024 + bi + tx];
    __syncthreads();
    for (int r = ty; r < 32; r += 8)
      wvtb[(long)(bi + r) * 1024 + bj + tx] = f2bf(tile[tx][r]);
  } else {  // bias fold
    const int row = (b - 10240) * 4 + (tid >> 6);
    const int lane = tid & 63;
    const float* w = Wp + (long)row * 1024;
    float s = 0.f;
    for (int j = lane; j < 1024; j += 64) s += w[j] * bv[j];
    for (int off = 32; off; off >>= 1) s += __shfl_down(s, off, 64);
    if (lane == 0) cv[row] = 2048.f * s + bp[row];
  }
}

// ---------------------------------------------------------------------
// reduce 4 split-K fp32 partial slabs -> bf16, *2048
__global__ void k_reduce(const float* __restrict__ p, u16* __restrict__ dst) {
  const long i = (long)(blockIdx.x * 256 + threadIdx.x) * 4;
  const float4 a = *(const float4*)(p + i);
  const float4 b = *(const float4*)(p + 1048576 + i);
  const float4 c = *(const float4*)(p + 2097152 + i);
  const float4 d = *(const float4*)(p + 3145728 + i);
  ushort4 o;
  o.x = f2bf((a.x + b.x + c.x + d.x) * 2048.f);
  o.y = f2bf((a.y + b.y + c.y + d.y) * 2048.f);
  o.z = f2bf((a.z + b.z + c.z + d.z) * 2048.f);
  o.w = f2bf((a.w + b.w + c.w + d.w) * 2048.f);
  *(ushort4*)(dst + i) = o;
}

// ---------------------------------------------------------------------
// NT bf16 GEMM: Out[M,N] (+bias) = A[M,K] @ B[N,K]^T
// BM=128, BK=32, BN template (64 or 128). 256 threads = 4 waves.
//   BN=128: waves 2x2, each 64x64 (acc 4x4)  -- used for GEMM1
//   BN=64 : waves 2x2, each 64x32 (acc 4x2)  -- used for GEMM2, 4 blk/CU
// MODE 0: fp32 out + bias.  MODE 1: fp32 partial slab at z*M*N (split-K).
template <int BN, int MODE>
__global__ __launch_bounds__(256, BN == 64 ? 4 : 3) void k_gemm(
    const u16* __restrict__ A, const u16* __restrict__ B, float* __restrict__ Out,
    const float* __restrict__ bias, int M, int N, int K) {
  constexpr int NT = BN / 32;  // n-tiles per wave
  __shared__ u16 As[128 * 32];
  __shared__ u16 Bs[BN * 32];

  const int tid = threadIdx.x;
  const int lane = tid & 63;
  const int wv = tid >> 6;
  const int waveM = (wv & 1) << 6;          // 0 / 64
  const int waveN = (wv >> 1) * (BN / 2);   // BN=64: 0/32 ; BN=128: 0/64
  const int l15 = lane & 15;
  const int quad = lane >> 4;

  const long bm = (long)blockIdx.x * 128;
  const long bn = (long)blockIdx.y * BN;
  const int kChunk = K / gridDim.z;
  const int kBeg = blockIdx.z * kChunk;
  const int kEnd = kBeg + kChunk;

  // staging map: thread tid handles 16B chunk = row (tid>>2), col (tid&3)*8
  const int srow = tid >> 2;
  const int scol = (tid & 3) << 3;
  const u16* Ag = A + (bm + srow) * K + scol;
  const u16* Bg = B + (bn + srow) * K + scol;
  u16* As0 = As + wv * 512;          // wave-uniform LDS bases (+lane*16B)
  u16* As1 = As + 2048 + wv * 512;
  u16* Bs0 = Bs + wv * 512;

  const f32x4 zero = {0.f, 0.f, 0.f, 0.f};
  f32x4 acc[4][NT];
#pragma unroll
  for (int i = 0; i < 4; ++i)
#pragma unroll
    for (int j = 0; j < NT; ++j) acc[i][j] = zero;

  for (int k0 = kBeg; k0 < kEnd; k0 += 32) {
    __syncthreads();  // previous tile fully consumed
    load16(Ag + k0, As0);
    load16(Ag + (long)64 * K + k0, As1);
    load16(Bg + k0, Bs0);
    if constexpr (BN == 128) load16(Bg + (long)64 * K + k0, Bs + 2048 + wv * 512);
    __syncthreads();  // staging drained (vmcnt(0) before s_barrier)

    bf16x8 af[4], bg[NT];
#pragma unroll
    for (int t = 0; t < 4; ++t)
      af[t] = *(const bf16x8*)(As + (waveM + t * 16 + l15) * 32 + quad * 8);
#pragma unroll
    for (int t = 0; t < NT; ++t)
      bg[t] = *(const bf16x8*)(Bs + (waveN + t * 16 + l15) * 32 + quad * 8);
#pragma unroll
    for (int i = 0; i < 4; ++i)
#pragma unroll
      for (int j = 0; j < NT; ++j)
        acc[i][j] = __builtin_amdgcn_mfma_f32_16x16x32_bf16(af[i], bg[j], acc[i][j], 0, 0, 0);
  }

  // epilogue: C/D layout col = lane&15, row = quad*4 + reg  [m89/m91]
  float* outp = (MODE == 1) ? Out + (long)blockIdx.z * M * N : Out;
#pragma unroll
  for (int i = 0; i < 4; ++i) {
    const long gm = bm + waveM + i * 16 + quad * 4;
#pragma unroll
    for (int j = 0; j < NT; ++j) {
      const long gn = bn + waveN + j * 16 + l15;
      const float bb = (MODE == 0) ? bias[gn] : 0.f;
#pragma unroll
      for (int r = 0; r < 4; ++r)
        outp[(gm + r) * N + gn] = acc[i][j][r] + bb;
    }
  }
}

// =====================================================================
extern "C" void kernel_launch(void* const* d_in, const int* in_sizes, int n_in,
                              void* d_out, int out_size, void* d_ws, size_t ws_size,
                              hipStream_t stream) {
  // setup_inputs order: x, Wq, bq, Wk, bk, Wv, bv, Wp, bp
  const float* x  = (const float*)d_in[0];
  const float* Wv = (const float*)d_in[5];
  const float* bv = (const float*)d_in[6];
  const float* Wp = (const float*)d_in[7];
  const float* bp = (const float*)d_in[8];

  char* ws = (char*)d_ws;
  u16* xb    = (u16*)(ws);                      // 16 MB  x bf16
  u16* wpb   = (u16*)(ws + (16u << 20));        //  2 MB  Wp bf16
  u16* wvtb  = (u16*)(ws + (18u << 20));        //  2 MB  Wv^T bf16
  u16* m2b   = (u16*)(ws + (20u << 20));        //  2 MB  M2 bf16
  float* cv  = (float*)(ws + (22u << 20));      //  4 KB  folded bias
  float* m2f = (float*)(ws + (22u << 20) + 4096);  // 16 MB split-K partials

  // 1) fused prep: conv x / conv Wp / transpose Wv / bias fold
  k_prep<<<10496, 256, 0, stream>>>(x, Wv, bv, Wp, bp, xb, wpb, wvtb, cv);

  // 2) M2 partials = Wp @ Wv  (split-K=4: 256 blocks, 1/CU)
  k_gemm<128, 1><<<dim3(8, 8, 4), 256, 0, stream>>>(wpb, wvtb, m2f, nullptr,
                                                    1024, 1024, 1024);
  // 3) M2 = bf16(2048 * sum of partials)
  k_reduce<<<1024, 256, 0, stream>>>(m2f, m2b);

  // 4) out = x @ M2^T + cv   (128x64 tiles: 1024 blocks, 4/CU)
  k_gemm<64, 0><<<dim3(64, 16, 1), 256, 0, stream>>>(xb, m2b, (float*)d_out, cv,
                                                     8192, 1024, 1024);
}